// Round 1
// baseline (47.340 us; speedup 1.0000x reference)
//
#include <hip/hip_runtime.h>
#include <math.h>

// Canny NMS magnitude extractor, fully fused.
// x: [16,3,512,512] f32 -> out: [16,3,512,512] f32 (same edge map in all 3 channels)

#define HH 512
#define WW 512
#define NB 16
#define TS 64          // output tile
#define GT 72          // gray tile  (TS + 2*4 halo)
#define BT 68          // blur tile  (TS + 2*2 halo)
#define MT 66          // mag tile   (TS + 2*1 halo)

__device__ __forceinline__ int reflect_i(int i, int n) {
    // numpy 'reflect' (no edge repeat), valid for pad <= n-1
    if (i < 0) i = -i;
    if (i >= n) i = 2 * n - 2 - i;
    return i;
}

__global__ __launch_bounds__(256, 4)
void canny_fused_kernel(const float* __restrict__ in, float* __restrict__ out) {
    const int tx0 = blockIdx.x * TS;
    const int ty0 = blockIdx.y * TS;
    const int b   = blockIdx.z;
    const int tid = threadIdx.x;

    __shared__ float sG[GT * GT];   // gray tile; reused as mag tile in phase 3/4
    __shared__ float sB[BT * BT];   // blur tile
    float* sMag = sG;

    // Gaussian 5x5 weights, computed exactly as the reference does in f32:
    // g1 = expf(-0.5*a*a) for a in {-2..2}; normalize by f32 sum; outer product.
    float g1[5];
    {
        float s = 0.f;
        #pragma unroll
        for (int i = 0; i < 5; ++i) {
            float a = (float)i - 2.0f;
            g1[i] = expf(-0.5f * a * a);
            s += g1[i];
        }
        #pragma unroll
        for (int i = 0; i < 5; ++i) g1[i] = g1[i] / s;
    }
    float w2d[25];
    #pragma unroll
    for (int j = 0; j < 5; ++j)
        #pragma unroll
        for (int i = 0; i < 5; ++i)
            w2d[j * 5 + i] = g1[j] * g1[i];

    const float* inb = in + (size_t)b * 3 * HH * WW;

    // -------- Phase 1: grayscale into LDS, reflect-mapped, raw coords [ty0-4, ty0+67]
    for (int s = tid; s < GT * GT; s += 256) {
        int j = s / GT, i = s - j * GT;
        int y = reflect_i(ty0 - 4 + j, HH);
        int x = reflect_i(tx0 - 4 + i, WW);
        const float* p = inb + y * WW + x;
        sG[s] = p[0] * 0.299f + p[HH * WW] * 0.587f + p[2 * HH * WW] * 0.114f;
    }
    __syncthreads();

    // -------- Phase 2: 5x5 gaussian blur at CLAMPED coords (gives sobel its edge/replicate pad)
    for (int s = tid; s < BT * BT; s += 256) {
        int j = s / BT, i = s - j * BT;
        int yc = min(max(ty0 - 2 + j, 0), HH - 1);
        int xc = min(max(tx0 - 2 + i, 0), WW - 1);
        int lj = yc - (ty0 - 4);   // gray-tile row of yc
        int li = xc - (tx0 - 4);
        float acc = 0.f;
        #pragma unroll
        for (int ky = 0; ky < 5; ++ky)
            #pragma unroll
            for (int kx = 0; kx < 5; ++kx)
                acc += w2d[ky * 5 + kx] * sG[(lj + ky - 2) * GT + (li + kx - 2)];
        sB[s] = acc;
    }
    __syncthreads();

    // -------- Phase 3: sobel magnitude, raw coords [ty0-1, ty0+64]; 0 outside image (NMS zero-pad).
    // Overwrites sG (gray no longer needed past the barrier above).
    for (int s = tid; s < MT * MT; s += 256) {
        int j = s / MT, i = s - j * MT;
        int y = ty0 - 1 + j;
        int x = tx0 - 1 + i;
        float m = 0.f;
        if (y >= 0 && y < HH && x >= 0 && x < WW) {
            int lj = y - (ty0 - 2);   // blur-tile row
            int li = x - (tx0 - 2);
            float b00 = sB[(lj - 1) * BT + (li - 1)];
            float b01 = sB[(lj - 1) * BT + li];
            float b02 = sB[(lj - 1) * BT + (li + 1)];
            float b10 = sB[lj * BT + (li - 1)];
            float b12 = sB[lj * BT + (li + 1)];
            float b20 = sB[(lj + 1) * BT + (li - 1)];
            float b21 = sB[(lj + 1) * BT + li];
            float b22 = sB[(lj + 1) * BT + (li + 1)];
            float gx = ((((-b00 + b02) - 2.f * b10) + 2.f * b12) - b20) + b22;
            float gy = ((((-b00 - 2.f * b01) - b02) + b20) + 2.f * b21) + b22;
            m = sqrtf(gx * gx + gy * gy + 1e-6f);
        }
        sMag[s] = m;
    }
    __syncthreads();

    // -------- Phase 4: angle bin + NMS + clip + write x3 channels
    for (int s = tid; s < TS * TS; s += 256) {
        int j = s >> 6, i = s & 63;
        int y = ty0 + j, x = tx0 + i;
        int lj = j + 2, li = i + 2;   // blur-tile coords of (y,x)
        float b00 = sB[(lj - 1) * BT + (li - 1)];
        float b01 = sB[(lj - 1) * BT + li];
        float b02 = sB[(lj - 1) * BT + (li + 1)];
        float b10 = sB[lj * BT + (li - 1)];
        float b12 = sB[lj * BT + (li + 1)];
        float b20 = sB[(lj + 1) * BT + (li - 1)];
        float b21 = sB[(lj + 1) * BT + li];
        float b22 = sB[(lj + 1) * BT + (li + 1)];
        float gx = ((((-b00 + b02) - 2.f * b10) + 2.f * b12) - b20) + b22;
        float gy = ((((-b00 - 2.f * b01) - b02) + b20) + 2.f * b21) + b22;

        // ang_bin = round(degrees(atan2(gy,gx))/45), round-half-even like jnp.round
        float t = atan2f(gy, gx) * 57.29577951308232f;
        t = t / 45.0f;
        int bin = (int)rintf(t);
        int pos = (bin + 8) & 7;      // jnp.mod(bin, 8), bin in [-4,4]

        // offsets[(i+4)%8] == -offsets[i], so only look up pos and negate.
        // (dy+1),(dx+1) packed 2 bits per direction.
        int dyp = ((425   >> (2 * pos)) & 3) - 1;
        int dxp = ((36890 >> (2 * pos)) & 3) - 1;

        float mc     = sMag[(j + 1) * MT + (i + 1)];
        float cs_pos = mc - sMag[(j + 1 + dyp) * MT + (i + 1 + dxp)];
        float cs_neg = mc - sMag[(j + 1 - dyp) * MT + (i + 1 - dxp)];
        float v = (fminf(cs_pos, cs_neg) > 0.0f) ? fminf(mc, 1.0f) : 0.0f;

        float* op = out + ((size_t)(b * 3) * HH + y) * WW + x;
        op[0] = v;
        op[(size_t)HH * WW] = v;
        op[(size_t)2 * HH * WW] = v;
    }
}

extern "C" void kernel_launch(void* const* d_in, const int* in_sizes, int n_in,
                              void* d_out, int out_size, void* d_ws, size_t ws_size,
                              hipStream_t stream) {
    const float* x = (const float*)d_in[0];
    float* out = (float*)d_out;
    dim3 grid(WW / TS, HH / TS, NB);
    dim3 block(256);
    hipLaunchKernelGGL(canny_fused_kernel, grid, block, 0, stream, x, out);
}